// Round 6
// baseline (242.079 us; speedup 1.0000x reference)
//
#include <hip/hip_runtime.h>
#include <hip/hip_bf16.h>
#include <cstdint>

// Causal self-attention: x[4,2048,1024] @ Wqkv[1024,3072] -> QKV -> 16-head
// causal attention (HD=64) -> @ Wout[1024,1024] -> out fp32.
// R6: attention back to R4 structure (64-row q-blocks, 4 waves) but with the
// P->PV transpose done by PERMUTING V's key order at the QKV epilogue: the
// softmax register layout then feeds PV's A-fragment directly (bit-cast of
// cvt_pk words). No P LDS buffer, no mid-iteration lgkmcnt drain. LDS 32KB ->
// 4-5 blocks/CU. GEMMs keep R5's m97 structure (global_load_lds width=16).

typedef __attribute__((ext_vector_type(8))) short bf16x8;
typedef __attribute__((ext_vector_type(4))) float f32x4;
typedef __attribute__((ext_vector_type(4))) uint32_t u32x4;

#define MFMA_BF16(a, b, c) __builtin_amdgcn_mfma_f32_16x16x32_bf16((a), (b), (c), 0, 0, 0)

__device__ __forceinline__ ushort f2bf(float f) {
  union { float f; uint32_t u; } x;
  x.f = f;
  uint32_t u = x.u;
  return (ushort)((u + 0x7FFFu + ((u >> 16) & 1u)) >> 16);
}

__device__ __forceinline__ uint32_t cvt_pk_bf16(float lo, float hi) {
  uint32_t r;
  asm("v_cvt_pk_bf16_f32 %0, %1, %2" : "=v"(r) : "v"(lo), "v"(hi));
  return r;
}

__device__ __forceinline__ void gload16(const ushort* g, ushort* l) {
  __builtin_amdgcn_global_load_lds(
      (const __attribute__((address_space(1))) void*)g,
      (__attribute__((address_space(3))) void*)l, 16, 0, 0);
}

// ---------------------------------------------------------------- convert x
__global__ __launch_bounds__(256) void convert_f32_bf16(
    const float* __restrict__ in, ushort* __restrict__ out, int n4) {
  int i = blockIdx.x * 256 + threadIdx.x;
  if (i < n4) {
    float4 v = ((const float4*)in)[i];
    ushort4 o;
    o.x = f2bf(v.x); o.y = f2bf(v.y); o.z = f2bf(v.z); o.w = f2bf(v.w);
    ((ushort4*)out)[i] = o;
  }
}

// ------------------------------------------------- W [K][N] f32 -> Wt [N][K] bf16
__global__ __launch_bounds__(256) void transpose_w(
    const float* __restrict__ W, ushort* __restrict__ Wt, int K, int N) {
  __shared__ float tile[32][33];
  const int n0 = blockIdx.x * 32, k0 = blockIdx.y * 32;
  const int tx = threadIdx.x & 31, ty = threadIdx.x >> 5;  // ty 0..7
#pragma unroll
  for (int i = 0; i < 4; ++i)
    tile[ty + i * 8][tx] = W[(size_t)(k0 + ty + i * 8) * N + n0 + tx];
  __syncthreads();
#pragma unroll
  for (int i = 0; i < 4; ++i)
    Wt[(size_t)(n0 + ty + i * 8) * K + k0 + tx] = f2bf(tile[tx][ty + i * 8]);
}

// ---------------------------------------------------------------- GEMM bf16
// A [M][K] bf16 row-major, Bt [N][K] bf16 row-major (B transposed).
// m97 structure: linear LDS [128][32], global_load_lds dwordx4 staging.
// MODE 0: epilogue splits QKV -> q (pre-scaled by 0.125*log2e), k [BH][T][64]
//         bf16, v transposed [BH][64][T] with keys PERMUTED within 32-chunks
//         (pos = (t&~31) + ((t&12)>>2)*8 + ((t>>4)&1)*4 + (t&3)) so the
//         attention PV A-frag consumes softmax registers directly.
// MODE 1: epilogue stores fp32 C [M][N].
template <int MODE>
__global__ __launch_bounds__(256) void gemm_bf16_kernel(
    const ushort* __restrict__ A, const ushort* __restrict__ Bt,
    float* __restrict__ C,
    ushort* __restrict__ qb, ushort* __restrict__ kb, ushort* __restrict__ vb,
    int M, int N, int K) {
  __shared__ ushort As[128 * 32];
  __shared__ ushort Bs[128 * 32];
  const int tid = threadIdx.x;
  const int lane = tid & 63;
  const int w = tid >> 6;
  const int wr = w >> 1, wc = w & 1;
  const int l15 = lane & 15, lhi = lane >> 4;
  const int row0 = blockIdx.x * 128, col0 = blockIdx.y * 128;

  // staging geometry: wave w owns chunks {2w, 2w+1}; chunk = 16 rows x 32 cols
  const int ch = w * 2;
  const int lr = lane >> 2;           // row within chunk
  const int lc = (lane & 3) << 3;     // ushort col offset (16B granules)
  const ushort* ga0 = A  + (size_t)(row0 + ch * 16 + lr) * K + lc;
  const ushort* ga1 = A  + (size_t)(row0 + ch * 16 + 16 + lr) * K + lc;
  const ushort* gb0 = Bt + (size_t)(col0 + ch * 16 + lr) * K + lc;
  const ushort* gb1 = Bt + (size_t)(col0 + ch * 16 + 16 + lr) * K + lc;
  ushort* la0 = &As[ch * 512];
  ushort* la1 = &As[(ch + 1) * 512];
  ushort* lb0 = &Bs[ch * 512];
  ushort* lb1 = &Bs[(ch + 1) * 512];

  f32x4 acc[4][4] = {};

  for (int k0 = 0; k0 < K; k0 += 32) {
    gload16(ga0 + k0, la0);
    gload16(ga1 + k0, la1);
    gload16(gb0 + k0, lb0);
    gload16(gb1 + k0, lb1);
    __syncthreads();  // drains vmcnt(0): staged tile visible
    bf16x8 af[4], bfr[4];
#pragma unroll
    for (int m = 0; m < 4; ++m)
      af[m] = *(const bf16x8*)&As[(wr * 64 + m * 16 + l15) * 32 + lhi * 8];
#pragma unroll
    for (int n = 0; n < 4; ++n)
      bfr[n] = *(const bf16x8*)&Bs[(wc * 64 + n * 16 + l15) * 32 + lhi * 8];
    __builtin_amdgcn_s_setprio(1);
#pragma unroll
    for (int m = 0; m < 4; ++m)
#pragma unroll
      for (int n = 0; n < 4; ++n)
        acc[m][n] = MFMA_BF16(af[m], bfr[n], acc[m][n]);
    __builtin_amdgcn_s_setprio(0);
    __syncthreads();  // reads done before next-tile staging
  }

  if (MODE == 1) {
#pragma unroll
    for (int m = 0; m < 4; ++m) {
      const int r0 = row0 + wr * 64 + m * 16 + lhi * 4;
#pragma unroll
      for (int n = 0; n < 4; ++n) {
        const int c = col0 + wc * 64 + n * 16 + l15;
#pragma unroll
        for (int j = 0; j < 4; ++j)
          C[(size_t)(r0 + j) * N + c] = acc[m][n][j];
      }
    }
  } else {
    // QKV split epilogue. c in [0,3072): seg = c/1024 (q/k/v), h = (c%1024)/64, d = c%64
    const float QSCALE = 0.18033688011112042f;  // (1/sqrt(64)) * log2(e)
#pragma unroll
    for (int m = 0; m < 4; ++m) {
      const int r0 = row0 + wr * 64 + m * 16 + lhi * 4;  // global token row (4 consecutive)
      const int b_ = r0 >> 11;
      const int t0 = r0 & 2047;
#pragma unroll
      for (int n = 0; n < 4; ++n) {
        const int c = col0 + wc * 64 + n * 16 + l15;
        const int seg = c >> 10;
        const int cc = c & 1023;
        const int h = cc >> 6, d = cc & 63;
        const size_t bhi = (size_t)(b_ * 16 + h);
        if (seg == 0) {
#pragma unroll
          for (int j = 0; j < 4; ++j)
            qb[(bhi * 2048 + t0 + j) * 64 + d] = f2bf(acc[m][n][j] * QSCALE);
        } else if (seg == 1) {
#pragma unroll
          for (int j = 0; j < 4; ++j)
            kb[(bhi * 2048 + t0 + j) * 64 + d] = f2bf(acc[m][n][j]);
        } else {
          // permuted key position within the 32-token chunk (t0 % 4 == 0)
          const int pos = (t0 & ~31) + ((t0 & 12) << 1) + ((t0 >> 4) & 1) * 4;
          ushort4 pk;
          pk.x = f2bf(acc[m][n][0]);
          pk.y = f2bf(acc[m][n][1]);
          pk.z = f2bf(acc[m][n][2]);
          pk.w = f2bf(acc[m][n][3]);
          *(ushort4*)(vb + (bhi * 64 + d) * 2048 + pos) = pk;  // V^T [BH][64][Tperm]
        }
      }
    }
  }
}

// ------------------------------------------------------------- attention
// Q: [BH][2048][64] bf16 pre-scaled by 0.125*log2e.  K: [BH][2048][64] bf16.
// Vt: [BH][64][2048] bf16 (key-permuted).  Ab out: [B][T][H*64] bf16.
// Block bid: qt = 31 - bid/64 (longest-first), bh = bid & 63.
// 4 waves; wave w owns q rows [qt*64 + w*16, +16). K/V tiles staged in LDS
// (double-buffered, XOR-swizzled). Swapped QK^T -> in-register softmax ->
// P-frag bit-cast straight from cvt_pk words (V key-permutation absorbs the
// fragment transpose). exp2 domain, diagonal-only mask, defer-max THR=8.
__global__ __launch_bounds__(256) void attn_kernel(
    const ushort* __restrict__ Qb, const ushort* __restrict__ Kb,
    const ushort* __restrict__ Vt, ushort* __restrict__ Ab) {
  const int bid = blockIdx.x;
  const int qt = 31 - (bid >> 6);
  const int bh = bid & 63;
  const int tid = threadIdx.x;
  const int lane = tid & 63;
  const int w = tid >> 6;
  const int l15 = lane & 15, lhi = lane >> 4;
  const int qloc = qt * 64 + w * 16;

  __shared__ ushort Ks[2][64 * 64];  // swizzled: elem = key*64 + ((d/8)^(key&7))*8 + d%8
  __shared__ ushort Vs[2][64 * 64];  // swizzled: elem = d*64 + ((p/8)^(d&7))*8 + p%8

  const size_t qkbase = (size_t)bh * (2048 * 64);
  const size_t vtb = (size_t)bh * (64 * 2048);

  // staging geometry: wave w covers tile rows [w*16, w*16+16), 2 chunks of 8 rows
  const int srow = w * 16 + (lane >> 3);  // + j*8
  const int sd0 = lane & 7;               // 16B slot within 128B row

  bf16x8 qf[2];
#pragma unroll
  for (int kk = 0; kk < 2; ++kk)
    qf[kk] = *(const bf16x8*)(Qb + qkbase + (size_t)(qloc + l15) * 64 + kk * 32 + lhi * 8);

  // ---- prologue: stage tile 0
  uint4 kreg[2], vreg[2];
#pragma unroll
  for (int j = 0; j < 2; ++j) {
    const int row = srow + j * 8;
    kreg[j] = *(const uint4*)(Kb + qkbase + (size_t)row * 64 + sd0 * 8);
    vreg[j] = *(const uint4*)(Vt + vtb + (size_t)row * 2048 + sd0 * 8);
  }
#pragma unroll
  for (int j = 0; j < 2; ++j) {
    const int row = srow + j * 8;
    const int slot = (sd0 ^ (row & 7)) * 8;
    *(uint4*)&Ks[0][row * 64 + slot] = kreg[j];
    *(uint4*)&Vs[0][row * 64 + slot] = vreg[j];
  }
  __syncthreads();

  float m_state = -INFINITY, l_state = 0.f;
  f32x4 o[4] = {};
  const int qrow = qloc + l15;
  int cur = 0;

  for (int kbt = 0; kbt <= qt; ++kbt) {
    const int key0 = kbt * 64;
    const bool last = (kbt == qt);  // block-uniform

    // ---- issue prefetch loads for tile kbt+1 (latency hides under compute)
    if (!last) {
      const int nk0 = key0 + 64;
#pragma unroll
      for (int j = 0; j < 2; ++j) {
        const int row = srow + j * 8;
        kreg[j] = *(const uint4*)(Kb + qkbase + (size_t)(nk0 + row) * 64 + sd0 * 8);
        vreg[j] = *(const uint4*)(Vt + vtb + (size_t)row * 2048 + nk0 + sd0 * 8);
      }
    }

    // ---- S^T = K Q^T from LDS (lane: q-col l15, key rows kt*16+lhi*4+j)
    f32x4 s[4];
    __builtin_amdgcn_s_setprio(1);
#pragma unroll
    for (int kt = 0; kt < 4; ++kt) {
      const int krow = kt * 16 + l15;
      const int sw = krow & 7;
      bf16x8 kf0 = *(const bf16x8*)&Ks[cur][krow * 64 + ((lhi ^ sw) * 8)];
      bf16x8 kf1 = *(const bf16x8*)&Ks[cur][krow * 64 + (((4 + lhi) ^ sw) * 8)];
      f32x4 acc = {};
      acc = MFMA_BF16(kf0, qf[0], acc);
      acc = MFMA_BF16(kf1, qf[1], acc);
      s[kt] = acc;
    }
    __builtin_amdgcn_s_setprio(0);

    // ---- causal mask: only the diagonal tile needs it (wave-uniform branch)
    if (last) {
#pragma unroll
      for (int kt = 0; kt < 4; ++kt)
#pragma unroll
        for (int j = 0; j < 4; ++j) {
          const int key = key0 + kt * 16 + lhi * 4 + j;
          if (key > qrow) s[kt][j] = -INFINITY;
        }
    }

    // ---- tile max (exp2 domain; no scale mul)
    float t0 = fmaxf(fmaxf(s[0][0], s[0][1]), fmaxf(s[0][2], s[0][3]));
    float t1 = fmaxf(fmaxf(s[1][0], s[1][1]), fmaxf(s[1][2], s[1][3]));
    float t2 = fmaxf(fmaxf(s[2][0], s[2][1]), fmaxf(s[2][2], s[2][3]));
    float t3 = fmaxf(fmaxf(s[3][0], s[3][1]), fmaxf(s[3][2], s[3][3]));
    float tmax = fmaxf(fmaxf(t0, t1), fmaxf(t2, t3));
    tmax = fmaxf(tmax, __shfl_xor(tmax, 16));
    tmax = fmaxf(tmax, __shfl_xor(tmax, 32));

    // ---- defer-max: rescale only when the running max grows by > 8
    if (!__all(tmax <= m_state + 8.0f)) {
      const float mnew = fmaxf(m_state, tmax);
      const float alpha = exp2f(m_state - mnew);  // first tile: exp2(-inf)=0
      float a_[4];
#pragma unroll
      for (int j = 0; j < 4; ++j) a_[j] = __shfl(alpha, lhi * 4 + j);
#pragma unroll
      for (int n = 0; n < 4; ++n)
#pragma unroll
        for (int j = 0; j < 4; ++j) o[n][j] *= a_[j];
      l_state *= alpha;
      m_state = mnew;
    }

    // ---- exp2 + row-sum + pack P into registers (A-frag via V permutation)
    float lloc = 0.f;
    uint32_t pkw[8];
#pragma unroll
    for (int kt = 0; kt < 4; ++kt) {
      float p0 = exp2f(s[kt][0] - m_state);
      float p1 = exp2f(s[kt][1] - m_state);
      float p2 = exp2f(s[kt][2] - m_state);
      float p3 = exp2f(s[kt][3] - m_state);
      lloc += (p0 + p1) + (p2 + p3);
      pkw[kt * 2]     = cvt_pk_bf16(p0, p1);
      pkw[kt * 2 + 1] = cvt_pk_bf16(p2, p3);
    }
    lloc += __shfl_xor(lloc, 16);
    lloc += __shfl_xor(lloc, 32);
    l_state += lloc;

    u32x4 pw0 = {pkw[0], pkw[1], pkw[2], pkw[3]};
    u32x4 pw1 = {pkw[4], pkw[5], pkw[6], pkw[7]};
    bf16x8 pf[2];
    pf[0] = __builtin_bit_cast(bf16x8, pw0);  // keys(perm-pos) 0..31 of tile
    pf[1] = __builtin_bit_cast(bf16x8, pw1);  // keys(perm-pos) 32..63

    // ---- O += P V from LDS (register P-frags; V key-permuted to match)
    __builtin_amdgcn_s_setprio(1);
#pragma unroll
    for (int n = 0; n < 4; ++n) {
      const int vrow = n * 16 + l15;
      const int sw = vrow & 7;
#pragma unroll
      for (int ks = 0; ks < 2; ++ks) {
        bf16x8 vf = *(const bf16x8*)&Vs[cur][vrow * 64 + (((ks * 4 + lhi) ^ sw) * 8)];
        o[n] = MFMA_BF16(pf[ks], vf, o[n]);
      }
    }
    __builtin_amdgcn_s_setprio(0);

    // ---- commit prefetched tile to the other buffer; one barrier per iter
    if (!last) {
      const int nxt = cur ^ 1;
#pragma unroll
      for (int j = 0; j < 2; ++j) {
        const int row = srow + j * 8;
        const int slot = (sd0 ^ (row & 7)) * 8;
        *(uint4*)&Ks[nxt][row * 64 + slot] = kreg[j];
        *(uint4*)&Vs[nxt][row * 64 + slot] = vreg[j];
      }
      cur = nxt;
      __syncthreads();
    }
  }

  // ---- epilogue: normalize by l (state lives at lane=row), store bf16
  float linv[4];
#pragma unroll
  for (int j = 0; j < 4; ++j)
    linv[j] = 1.0f / __shfl(l_state, lhi * 4 + j);
  const int b_ = bh >> 4, h_ = bh & 15;
#pragma unroll
  for (int j = 0; j < 4; ++j) {
    const int t = qloc + lhi * 4 + j;
    const size_t ro = ((size_t)b_ * 2048 + t) * 1024 + h_ * 64;
#pragma unroll
    for (int n = 0; n < 4; ++n)
      Ab[ro + n * 16 + l15] = f2bf(o[n][j] * linv[j]);
  }
}

// ---------------------------------------------------------------- launch
extern "C" void kernel_launch(void* const* d_in, const int* in_sizes, int n_in,
                              void* d_out, int out_size, void* d_ws, size_t ws_size,
                              hipStream_t stream) {
  const float* x = (const float*)d_in[0];
  const float* Wqkv = (const float*)d_in[1];
  const float* Wout = (const float*)d_in[2];
  float* out = (float*)d_out;

  // workspace layout (bf16 elements), total ~88 MB
  ushort* xb    = (ushort*)d_ws;                     // [8192][1024]
  ushort* wqkvT = xb + (size_t)8192 * 1024;          // [3072][1024]
  ushort* woutT = wqkvT + (size_t)3072 * 1024;       // [1024][1024]
  ushort* qb    = woutT + (size_t)1024 * 1024;       // [64][2048][64]
  ushort* kbuf  = qb + (size_t)64 * 2048 * 64;       // [64][2048][64]
  ushort* vbuf  = kbuf + (size_t)64 * 2048 * 64;     // [64][64][2048] (V^T, key-permuted)
  ushort* ab    = vbuf + (size_t)64 * 2048 * 64;     // [8192][1024]

  convert_f32_bf16<<<8192, 256, 0, stream>>>(x, xb, 8192 * 1024 / 4);
  transpose_w<<<dim3(96, 32), 256, 0, stream>>>(Wqkv, wqkvT, 1024, 3072);
  transpose_w<<<dim3(32, 32), 256, 0, stream>>>(Wout, woutT, 1024, 1024);
  gemm_bf16_kernel<0><<<dim3(64, 24), 256, 0, stream>>>(
      xb, wqkvT, nullptr, qb, kbuf, vbuf, 8192, 3072, 1024);
  attn_kernel<<<2048, 256, 0, stream>>>(qb, kbuf, vbuf, ab);
  gemm_bf16_kernel<1><<<dim3(64, 8), 256, 0, stream>>>(
      ab, woutT, out, nullptr, nullptr, nullptr, 8192, 1024, 1024);
}

// Round 7
// 237.697 us; speedup vs baseline: 1.0184x; 1.0184x over previous
//
#include <hip/hip_runtime.h>
#include <hip/hip_bf16.h>
#include <cstdint>

// Causal self-attention: x[4,2048,1024] @ Wqkv[1024,3072] -> QKV -> 16-head
// causal attention (HD=64) -> @ Wout[1024,1024] -> out fp32.
// R7: identical dataflow to R6 (P-fragments in registers via key-permuted V,
// zero LDS bank conflicts, 32KB LDS) but with __launch_bounds__(256, 4) on
// attn_kernel: R6's compiler-chosen 56-VGPR budget spilled in the hot loop
// (WRITE_SIZE ~388MB of scratch writeback). Pinning 4 waves/EU -> 128 VGPR
// cap fits the ~110 live registers without spill.

typedef __attribute__((ext_vector_type(8))) short bf16x8;
typedef __attribute__((ext_vector_type(4))) float f32x4;
typedef __attribute__((ext_vector_type(4))) uint32_t u32x4;

#define MFMA_BF16(a, b, c) __builtin_amdgcn_mfma_f32_16x16x32_bf16((a), (b), (c), 0, 0, 0)

__device__ __forceinline__ ushort f2bf(float f) {
  union { float f; uint32_t u; } x;
  x.f = f;
  uint32_t u = x.u;
  return (ushort)((u + 0x7FFFu + ((u >> 16) & 1u)) >> 16);
}

__device__ __forceinline__ uint32_t cvt_pk_bf16(float lo, float hi) {
  uint32_t r;
  asm("v_cvt_pk_bf16_f32 %0, %1, %2" : "=v"(r) : "v"(lo), "v"(hi));
  return r;
}

__device__ __forceinline__ void gload16(const ushort* g, ushort* l) {
  __builtin_amdgcn_global_load_lds(
      (const __attribute__((address_space(1))) void*)g,
      (__attribute__((address_space(3))) void*)l, 16, 0, 0);
}

// ---------------------------------------------------------------- convert x
__global__ __launch_bounds__(256) void convert_f32_bf16(
    const float* __restrict__ in, ushort* __restrict__ out, int n4) {
  int i = blockIdx.x * 256 + threadIdx.x;
  if (i < n4) {
    float4 v = ((const float4*)in)[i];
    ushort4 o;
    o.x = f2bf(v.x); o.y = f2bf(v.y); o.z = f2bf(v.z); o.w = f2bf(v.w);
    ((ushort4*)out)[i] = o;
  }
}

// ------------------------------------------------- W [K][N] f32 -> Wt [N][K] bf16
__global__ __launch_bounds__(256) void transpose_w(
    const float* __restrict__ W, ushort* __restrict__ Wt, int K, int N) {
  __shared__ float tile[32][33];
  const int n0 = blockIdx.x * 32, k0 = blockIdx.y * 32;
  const int tx = threadIdx.x & 31, ty = threadIdx.x >> 5;  // ty 0..7
#pragma unroll
  for (int i = 0; i < 4; ++i)
    tile[ty + i * 8][tx] = W[(size_t)(k0 + ty + i * 8) * N + n0 + tx];
  __syncthreads();
#pragma unroll
  for (int i = 0; i < 4; ++i)
    Wt[(size_t)(n0 + ty + i * 8) * K + k0 + tx] = f2bf(tile[tx][ty + i * 8]);
}

// ---------------------------------------------------------------- GEMM bf16
// A [M][K] bf16 row-major, Bt [N][K] bf16 row-major (B transposed).
// m97 structure: linear LDS [128][32], global_load_lds dwordx4 staging.
// MODE 0: epilogue splits QKV -> q (pre-scaled by 0.125*log2e), k [BH][T][64]
//         bf16, v transposed [BH][64][T] with keys PERMUTED within 32-chunks
//         so the attention PV A-frag consumes softmax registers directly.
// MODE 1: epilogue stores fp32 C [M][N].
template <int MODE>
__global__ __launch_bounds__(256) void gemm_bf16_kernel(
    const ushort* __restrict__ A, const ushort* __restrict__ Bt,
    float* __restrict__ C,
    ushort* __restrict__ qb, ushort* __restrict__ kb, ushort* __restrict__ vb,
    int M, int N, int K) {
  __shared__ ushort As[128 * 32];
  __shared__ ushort Bs[128 * 32];
  const int tid = threadIdx.x;
  const int lane = tid & 63;
  const int w = tid >> 6;
  const int wr = w >> 1, wc = w & 1;
  const int l15 = lane & 15, lhi = lane >> 4;
  const int row0 = blockIdx.x * 128, col0 = blockIdx.y * 128;

  // staging geometry: wave w owns chunks {2w, 2w+1}; chunk = 16 rows x 32 cols
  const int ch = w * 2;
  const int lr = lane >> 2;           // row within chunk
  const int lc = (lane & 3) << 3;     // ushort col offset (16B granules)
  const ushort* ga0 = A  + (size_t)(row0 + ch * 16 + lr) * K + lc;
  const ushort* ga1 = A  + (size_t)(row0 + ch * 16 + 16 + lr) * K + lc;
  const ushort* gb0 = Bt + (size_t)(col0 + ch * 16 + lr) * K + lc;
  const ushort* gb1 = Bt + (size_t)(col0 + ch * 16 + 16 + lr) * K + lc;
  ushort* la0 = &As[ch * 512];
  ushort* la1 = &As[(ch + 1) * 512];
  ushort* lb0 = &Bs[ch * 512];
  ushort* lb1 = &Bs[(ch + 1) * 512];

  f32x4 acc[4][4] = {};

  for (int k0 = 0; k0 < K; k0 += 32) {
    gload16(ga0 + k0, la0);
    gload16(ga1 + k0, la1);
    gload16(gb0 + k0, lb0);
    gload16(gb1 + k0, lb1);
    __syncthreads();  // drains vmcnt(0): staged tile visible
    bf16x8 af[4], bfr[4];
#pragma unroll
    for (int m = 0; m < 4; ++m)
      af[m] = *(const bf16x8*)&As[(wr * 64 + m * 16 + l15) * 32 + lhi * 8];
#pragma unroll
    for (int n = 0; n < 4; ++n)
      bfr[n] = *(const bf16x8*)&Bs[(wc * 64 + n * 16 + l15) * 32 + lhi * 8];
    __builtin_amdgcn_s_setprio(1);
#pragma unroll
    for (int m = 0; m < 4; ++m)
#pragma unroll
      for (int n = 0; n < 4; ++n)
        acc[m][n] = MFMA_BF16(af[m], bfr[n], acc[m][n]);
    __builtin_amdgcn_s_setprio(0);
    __syncthreads();  // reads done before next-tile staging
  }

  if (MODE == 1) {
#pragma unroll
    for (int m = 0; m < 4; ++m) {
      const int r0 = row0 + wr * 64 + m * 16 + lhi * 4;
#pragma unroll
      for (int n = 0; n < 4; ++n) {
        const int c = col0 + wc * 64 + n * 16 + l15;
#pragma unroll
        for (int j = 0; j < 4; ++j)
          C[(size_t)(r0 + j) * N + c] = acc[m][n][j];
      }
    }
  } else {
    // QKV split epilogue. c in [0,3072): seg = c/1024 (q/k/v), h = (c%1024)/64, d = c%64
    const float QSCALE = 0.18033688011112042f;  // (1/sqrt(64)) * log2(e)
#pragma unroll
    for (int m = 0; m < 4; ++m) {
      const int r0 = row0 + wr * 64 + m * 16 + lhi * 4;  // global token row (4 consecutive)
      const int b_ = r0 >> 11;
      const int t0 = r0 & 2047;
#pragma unroll
      for (int n = 0; n < 4; ++n) {
        const int c = col0 + wc * 64 + n * 16 + l15;
        const int seg = c >> 10;
        const int cc = c & 1023;
        const int h = cc >> 6, d = cc & 63;
        const size_t bhi = (size_t)(b_ * 16 + h);
        if (seg == 0) {
#pragma unroll
          for (int j = 0; j < 4; ++j)
            qb[(bhi * 2048 + t0 + j) * 64 + d] = f2bf(acc[m][n][j] * QSCALE);
        } else if (seg == 1) {
#pragma unroll
          for (int j = 0; j < 4; ++j)
            kb[(bhi * 2048 + t0 + j) * 64 + d] = f2bf(acc[m][n][j]);
        } else {
          // permuted key position within the 32-token chunk (t0 % 4 == 0)
          const int pos = (t0 & ~31) + ((t0 & 12) << 1) + ((t0 >> 4) & 1) * 4;
          ushort4 pk;
          pk.x = f2bf(acc[m][n][0]);
          pk.y = f2bf(acc[m][n][1]);
          pk.z = f2bf(acc[m][n][2]);
          pk.w = f2bf(acc[m][n][3]);
          *(ushort4*)(vb + (bhi * 64 + d) * 2048 + pos) = pk;  // V^T [BH][64][Tperm]
        }
      }
    }
  }
}

// ------------------------------------------------------------- attention
// Q: [BH][2048][64] bf16 pre-scaled by 0.125*log2e.  K: [BH][2048][64] bf16.
// Vt: [BH][64][2048] bf16 (key-permuted).  Ab out: [B][T][H*64] bf16.
// Block bid: qt = 31 - bid/64 (longest-first), bh = bid & 63.
// 4 waves; wave w owns q rows [qt*64 + w*16, +16). K/V tiles staged in LDS
// (double-buffered, XOR-swizzled). Swapped QK^T -> in-register softmax ->
// P-frag bit-cast straight from cvt_pk words (V key-permutation absorbs the
// fragment transpose). exp2 domain, diagonal-only mask, defer-max THR=8.
// __launch_bounds__(256, 4): pin 128-VGPR budget (R6's 56-VGPR choice spilled).
__global__ __launch_bounds__(256, 4) void attn_kernel(
    const ushort* __restrict__ Qb, const ushort* __restrict__ Kb,
    const ushort* __restrict__ Vt, ushort* __restrict__ Ab) {
  const int bid = blockIdx.x;
  const int qt = 31 - (bid >> 6);
  const int bh = bid & 63;
  const int tid = threadIdx.x;
  const int lane = tid & 63;
  const int w = tid >> 6;
  const int l15 = lane & 15, lhi = lane >> 4;
  const int qloc = qt * 64 + w * 16;

  __shared__ ushort Ks[2][64 * 64];  // swizzled: elem = key*64 + ((d/8)^(key&7))*8 + d%8
  __shared__ ushort Vs[2][64 * 64];  // swizzled: elem = d*64 + ((p/8)^(d&7))*8 + p%8

  const size_t qkbase = (size_t)bh * (2048 * 64);
  const size_t vtb = (size_t)bh * (64 * 2048);

  // staging geometry: wave w covers tile rows [w*16, w*16+16), 2 chunks of 8 rows
  const int srow = w * 16 + (lane >> 3);  // + j*8
  const int sd0 = lane & 7;               // 16B slot within 128B row

  bf16x8 qf[2];
#pragma unroll
  for (int kk = 0; kk < 2; ++kk)
    qf[kk] = *(const bf16x8*)(Qb + qkbase + (size_t)(qloc + l15) * 64 + kk * 32 + lhi * 8);

  // ---- prologue: stage tile 0
  uint4 kreg[2], vreg[2];
#pragma unroll
  for (int j = 0; j < 2; ++j) {
    const int row = srow + j * 8;
    kreg[j] = *(const uint4*)(Kb + qkbase + (size_t)row * 64 + sd0 * 8);
    vreg[j] = *(const uint4*)(Vt + vtb + (size_t)row * 2048 + sd0 * 8);
  }
#pragma unroll
  for (int j = 0; j < 2; ++j) {
    const int row = srow + j * 8;
    const int slot = (sd0 ^ (row & 7)) * 8;
    *(uint4*)&Ks[0][row * 64 + slot] = kreg[j];
    *(uint4*)&Vs[0][row * 64 + slot] = vreg[j];
  }
  __syncthreads();

  float m_state = -INFINITY, l_state = 0.f;
  f32x4 o[4] = {};
  const int qrow = qloc + l15;
  int cur = 0;

  for (int kbt = 0; kbt <= qt; ++kbt) {
    const int key0 = kbt * 64;
    const bool last = (kbt == qt);  // block-uniform

    // ---- issue prefetch loads for tile kbt+1 (latency hides under compute)
    if (!last) {
      const int nk0 = key0 + 64;
#pragma unroll
      for (int j = 0; j < 2; ++j) {
        const int row = srow + j * 8;
        kreg[j] = *(const uint4*)(Kb + qkbase + (size_t)(nk0 + row) * 64 + sd0 * 8);
        vreg[j] = *(const uint4*)(Vt + vtb + (size_t)row * 2048 + nk0 + sd0 * 8);
      }
    }

    // ---- S^T = K Q^T from LDS (lane: q-col l15, key rows kt*16+lhi*4+j)
    f32x4 s[4];
    __builtin_amdgcn_s_setprio(1);
#pragma unroll
    for (int kt = 0; kt < 4; ++kt) {
      const int krow = kt * 16 + l15;
      const int sw = krow & 7;
      bf16x8 kf0 = *(const bf16x8*)&Ks[cur][krow * 64 + ((lhi ^ sw) * 8)];
      bf16x8 kf1 = *(const bf16x8*)&Ks[cur][krow * 64 + (((4 + lhi) ^ sw) * 8)];
      f32x4 acc = {};
      acc = MFMA_BF16(kf0, qf[0], acc);
      acc = MFMA_BF16(kf1, qf[1], acc);
      s[kt] = acc;
    }
    __builtin_amdgcn_s_setprio(0);

    // ---- causal mask: only the diagonal tile needs it (wave-uniform branch)
    if (last) {
#pragma unroll
      for (int kt = 0; kt < 4; ++kt)
#pragma unroll
        for (int j = 0; j < 4; ++j) {
          const int key = key0 + kt * 16 + lhi * 4 + j;
          if (key > qrow) s[kt][j] = -INFINITY;
        }
    }

    // ---- tile max (exp2 domain; no scale mul)
    float t0 = fmaxf(fmaxf(s[0][0], s[0][1]), fmaxf(s[0][2], s[0][3]));
    float t1 = fmaxf(fmaxf(s[1][0], s[1][1]), fmaxf(s[1][2], s[1][3]));
    float t2 = fmaxf(fmaxf(s[2][0], s[2][1]), fmaxf(s[2][2], s[2][3]));
    float t3 = fmaxf(fmaxf(s[3][0], s[3][1]), fmaxf(s[3][2], s[3][3]));
    float tmax = fmaxf(fmaxf(t0, t1), fmaxf(t2, t3));
    tmax = fmaxf(tmax, __shfl_xor(tmax, 16));
    tmax = fmaxf(tmax, __shfl_xor(tmax, 32));

    // ---- defer-max: rescale only when the running max grows by > 8
    if (!__all(tmax <= m_state + 8.0f)) {
      const float mnew = fmaxf(m_state, tmax);
      const float alpha = exp2f(m_state - mnew);  // first tile: exp2(-inf)=0
      float a_[4];
#pragma unroll
      for (int j = 0; j < 4; ++j) a_[j] = __shfl(alpha, lhi * 4 + j);
#pragma unroll
      for (int n = 0; n < 4; ++n)
#pragma unroll
        for (int j = 0; j < 4; ++j) o[n][j] *= a_[j];
      l_state *= alpha;
      m_state = mnew;
    }

    // ---- exp2 + row-sum + pack P into registers (A-frag via V permutation)
    float lloc = 0.f;
    uint32_t pkw[8];
#pragma unroll
    for (int kt = 0; kt < 4; ++kt) {
      float p0 = exp2f(s[kt][0] - m_state);
      float p1 = exp2f(s[kt][1] - m_state);
      float p2 = exp2f(s[kt][2] - m_state);
      float p3 = exp2f(s[kt][3] - m_state);
      lloc += (p0 + p1) + (p2 + p3);
      pkw[kt * 2]     = cvt_pk_bf16(p0, p1);
      pkw[kt * 2 + 1] = cvt_pk_bf16(p2, p3);
    }
    lloc += __shfl_xor(lloc, 16);
    lloc += __shfl_xor(lloc, 32);
    l_state += lloc;

    u32x4 pw0 = {pkw[0], pkw[1], pkw[2], pkw[3]};
    u32x4 pw1 = {pkw[4], pkw[5], pkw[6], pkw[7]};
    bf16x8 pf[2];
    pf[0] = __builtin_bit_cast(bf16x8, pw0);  // keys(perm-pos) 0..31 of tile
    pf[1] = __builtin_bit_cast(bf16x8, pw1);  // keys(perm-pos) 32..63

    // ---- O += P V from LDS (register P-frags; V key-permuted to match)
    __builtin_amdgcn_s_setprio(1);
#pragma unroll
    for (int n = 0; n < 4; ++n) {
      const int vrow = n * 16 + l15;
      const int sw = vrow & 7;
#pragma unroll
      for (int ks = 0; ks < 2; ++ks) {
        bf16x8 vf = *(const bf16x8*)&Vs[cur][vrow * 64 + (((ks * 4 + lhi) ^ sw) * 8)];
        o[n] = MFMA_BF16(pf[ks], vf, o[n]);
      }
    }
    __builtin_amdgcn_s_setprio(0);

    // ---- commit prefetched tile to the other buffer; one barrier per iter
    if (!last) {
      const int nxt = cur ^ 1;
#pragma unroll
      for (int j = 0; j < 2; ++j) {
        const int row = srow + j * 8;
        const int slot = (sd0 ^ (row & 7)) * 8;
        *(uint4*)&Ks[nxt][row * 64 + slot] = kreg[j];
        *(uint4*)&Vs[nxt][row * 64 + slot] = vreg[j];
      }
      cur = nxt;
      __syncthreads();
    }
  }

  // ---- epilogue: normalize by l (state lives at lane=row), store bf16
  float linv[4];
#pragma unroll
  for (int j = 0; j < 4; ++j)
    linv[j] = 1.0f / __shfl(l_state, lhi * 4 + j);
  const int b_ = bh >> 4, h_ = bh & 15;
#pragma unroll
  for (int j = 0; j < 4; ++j) {
    const int t = qloc + lhi * 4 + j;
    const size_t ro = ((size_t)b_ * 2048 + t) * 1024 + h_ * 64;
#pragma unroll
    for (int n = 0; n < 4; ++n)
      Ab[ro + n * 16 + l15] = f2bf(o[n][j] * linv[j]);
  }
}

// ---------------------------------------------------------------- launch
extern "C" void kernel_launch(void* const* d_in, const int* in_sizes, int n_in,
                              void* d_out, int out_size, void* d_ws, size_t ws_size,
                              hipStream_t stream) {
  const float* x = (const float*)d_in[0];
  const float* Wqkv = (const float*)d_in[1];
  const float* Wout = (const float*)d_in[2];
  float* out = (float*)d_out;

  // workspace layout (bf16 elements), total ~88 MB
  ushort* xb    = (ushort*)d_ws;                     // [8192][1024]
  ushort* wqkvT = xb + (size_t)8192 * 1024;          // [3072][1024]
  ushort* woutT = wqkvT + (size_t)3072 * 1024;       // [1024][1024]
  ushort* qb    = woutT + (size_t)1024 * 1024;       // [64][2048][64]
  ushort* kbuf  = qb + (size_t)64 * 2048 * 64;       // [64][2048][64]
  ushort* vbuf  = kbuf + (size_t)64 * 2048 * 64;     // [64][64][2048] (V^T, key-permuted)
  ushort* ab    = vbuf + (size_t)64 * 2048 * 64;     // [8192][1024]

  convert_f32_bf16<<<8192, 256, 0, stream>>>(x, xb, 8192 * 1024 / 4);
  transpose_w<<<dim3(96, 32), 256, 0, stream>>>(Wqkv, wqkvT, 1024, 3072);
  transpose_w<<<dim3(32, 32), 256, 0, stream>>>(Wout, woutT, 1024, 1024);
  gemm_bf16_kernel<0><<<dim3(64, 24), 256, 0, stream>>>(
      xb, wqkvT, nullptr, qb, kbuf, vbuf, 8192, 3072, 1024);
  attn_kernel<<<2048, 256, 0, stream>>>(qb, kbuf, vbuf, ab);
  gemm_bf16_kernel<1><<<dim3(64, 8), 256, 0, stream>>>(
      ab, woutT, out, nullptr, nullptr, nullptr, 8192, 1024, 1024);
}

// Round 8
// 195.178 us; speedup vs baseline: 1.2403x; 1.2178x over previous
//
#include <hip/hip_runtime.h>
#include <hip/hip_bf16.h>
#include <cstdint>

// Causal self-attention: x[4,2048,1024] @ Wqkv[1024,3072] -> QKV -> 16-head
// causal attention (HD=64) -> @ Wout[1024,1024] -> out fp32.
// R8: same dataflow as R6/R7 (register P-frags via key-permuted V, zero bank
// conflicts) with the scratch-spill fixed two ways: (1) amdgpu_waves_per_eu(4,4)
// pins the allocator's occupancy TARGET (launch_bounds' 2nd arg is only a
// minimum -> scheduler occupancy-chased to 8 waves and spilled, VGPR 48,
// WRITE_SIZE 433MB); (2) all hot-loop state de-arrayed into named values so
// SROA can never demote it to a scratch alloca.

typedef __attribute__((ext_vector_type(8))) short bf16x8;
typedef __attribute__((ext_vector_type(4))) float f32x4;
typedef __attribute__((ext_vector_type(4))) uint32_t u32x4;

#define MFMA_BF16(a, b, c) __builtin_amdgcn_mfma_f32_16x16x32_bf16((a), (b), (c), 0, 0, 0)

__device__ __forceinline__ ushort f2bf(float f) {
  union { float f; uint32_t u; } x;
  x.f = f;
  uint32_t u = x.u;
  return (ushort)((u + 0x7FFFu + ((u >> 16) & 1u)) >> 16);
}

__device__ __forceinline__ uint32_t cvt_pk_bf16(float lo, float hi) {
  uint32_t r;
  asm("v_cvt_pk_bf16_f32 %0, %1, %2" : "=v"(r) : "v"(lo), "v"(hi));
  return r;
}

__device__ __forceinline__ void gload16(const ushort* g, ushort* l) {
  __builtin_amdgcn_global_load_lds(
      (const __attribute__((address_space(1))) void*)g,
      (__attribute__((address_space(3))) void*)l, 16, 0, 0);
}

// ---------------------------------------------------------------- convert x
__global__ __launch_bounds__(256) void convert_f32_bf16(
    const float* __restrict__ in, ushort* __restrict__ out, int n4) {
  int i = blockIdx.x * 256 + threadIdx.x;
  if (i < n4) {
    float4 v = ((const float4*)in)[i];
    ushort4 o;
    o.x = f2bf(v.x); o.y = f2bf(v.y); o.z = f2bf(v.z); o.w = f2bf(v.w);
    ((ushort4*)out)[i] = o;
  }
}

// ------------------------------------------------- W [K][N] f32 -> Wt [N][K] bf16
__global__ __launch_bounds__(256) void transpose_w(
    const float* __restrict__ W, ushort* __restrict__ Wt, int K, int N) {
  __shared__ float tile[32][33];
  const int n0 = blockIdx.x * 32, k0 = blockIdx.y * 32;
  const int tx = threadIdx.x & 31, ty = threadIdx.x >> 5;  // ty 0..7
#pragma unroll
  for (int i = 0; i < 4; ++i)
    tile[ty + i * 8][tx] = W[(size_t)(k0 + ty + i * 8) * N + n0 + tx];
  __syncthreads();
#pragma unroll
  for (int i = 0; i < 4; ++i)
    Wt[(size_t)(n0 + ty + i * 8) * K + k0 + tx] = f2bf(tile[tx][ty + i * 8]);
}

// ---------------------------------------------------------------- GEMM bf16
// A [M][K] bf16 row-major, Bt [N][K] bf16 row-major (B transposed).
// m97 structure: linear LDS [128][32], global_load_lds dwordx4 staging.
// MODE 0: epilogue splits QKV -> q (pre-scaled by 0.125*log2e), k [BH][T][64]
//         bf16, v transposed [BH][64][T] with keys PERMUTED within 32-chunks
//         so the attention PV A-frag consumes softmax registers directly.
// MODE 1: epilogue stores fp32 C [M][N].
template <int MODE>
__global__ __launch_bounds__(256) void gemm_bf16_kernel(
    const ushort* __restrict__ A, const ushort* __restrict__ Bt,
    float* __restrict__ C,
    ushort* __restrict__ qb, ushort* __restrict__ kb, ushort* __restrict__ vb,
    int M, int N, int K) {
  __shared__ ushort As[128 * 32];
  __shared__ ushort Bs[128 * 32];
  const int tid = threadIdx.x;
  const int lane = tid & 63;
  const int w = tid >> 6;
  const int wr = w >> 1, wc = w & 1;
  const int l15 = lane & 15, lhi = lane >> 4;
  const int row0 = blockIdx.x * 128, col0 = blockIdx.y * 128;

  // staging geometry: wave w owns chunks {2w, 2w+1}; chunk = 16 rows x 32 cols
  const int ch = w * 2;
  const int lr = lane >> 2;           // row within chunk
  const int lc = (lane & 3) << 3;     // ushort col offset (16B granules)
  const ushort* ga0 = A  + (size_t)(row0 + ch * 16 + lr) * K + lc;
  const ushort* ga1 = A  + (size_t)(row0 + ch * 16 + 16 + lr) * K + lc;
  const ushort* gb0 = Bt + (size_t)(col0 + ch * 16 + lr) * K + lc;
  const ushort* gb1 = Bt + (size_t)(col0 + ch * 16 + 16 + lr) * K + lc;
  ushort* la0 = &As[ch * 512];
  ushort* la1 = &As[(ch + 1) * 512];
  ushort* lb0 = &Bs[ch * 512];
  ushort* lb1 = &Bs[(ch + 1) * 512];

  f32x4 acc[4][4] = {};

  for (int k0 = 0; k0 < K; k0 += 32) {
    gload16(ga0 + k0, la0);
    gload16(ga1 + k0, la1);
    gload16(gb0 + k0, lb0);
    gload16(gb1 + k0, lb1);
    __syncthreads();  // drains vmcnt(0): staged tile visible
    bf16x8 af[4], bfr[4];
#pragma unroll
    for (int m = 0; m < 4; ++m)
      af[m] = *(const bf16x8*)&As[(wr * 64 + m * 16 + l15) * 32 + lhi * 8];
#pragma unroll
    for (int n = 0; n < 4; ++n)
      bfr[n] = *(const bf16x8*)&Bs[(wc * 64 + n * 16 + l15) * 32 + lhi * 8];
    __builtin_amdgcn_s_setprio(1);
#pragma unroll
    for (int m = 0; m < 4; ++m)
#pragma unroll
      for (int n = 0; n < 4; ++n)
        acc[m][n] = MFMA_BF16(af[m], bfr[n], acc[m][n]);
    __builtin_amdgcn_s_setprio(0);
    __syncthreads();  // reads done before next-tile staging
  }

  if (MODE == 1) {
#pragma unroll
    for (int m = 0; m < 4; ++m) {
      const int r0 = row0 + wr * 64 + m * 16 + lhi * 4;
#pragma unroll
      for (int n = 0; n < 4; ++n) {
        const int c = col0 + wc * 64 + n * 16 + l15;
#pragma unroll
        for (int j = 0; j < 4; ++j)
          C[(size_t)(r0 + j) * N + c] = acc[m][n][j];
      }
    }
  } else {
    // QKV split epilogue. c in [0,3072): seg = c/1024 (q/k/v), h = (c%1024)/64, d = c%64
    const float QSCALE = 0.18033688011112042f;  // (1/sqrt(64)) * log2(e)
#pragma unroll
    for (int m = 0; m < 4; ++m) {
      const int r0 = row0 + wr * 64 + m * 16 + lhi * 4;  // global token row (4 consecutive)
      const int b_ = r0 >> 11;
      const int t0 = r0 & 2047;
#pragma unroll
      for (int n = 0; n < 4; ++n) {
        const int c = col0 + wc * 64 + n * 16 + l15;
        const int seg = c >> 10;
        const int cc = c & 1023;
        const int h = cc >> 6, d = cc & 63;
        const size_t bhi = (size_t)(b_ * 16 + h);
        if (seg == 0) {
#pragma unroll
          for (int j = 0; j < 4; ++j)
            qb[(bhi * 2048 + t0 + j) * 64 + d] = f2bf(acc[m][n][j] * QSCALE);
        } else if (seg == 1) {
#pragma unroll
          for (int j = 0; j < 4; ++j)
            kb[(bhi * 2048 + t0 + j) * 64 + d] = f2bf(acc[m][n][j]);
        } else {
          // permuted key position within the 32-token chunk (t0 % 4 == 0)
          const int pos = (t0 & ~31) + ((t0 & 12) << 1) + ((t0 >> 4) & 1) * 4;
          ushort4 pk;
          pk.x = f2bf(acc[m][n][0]);
          pk.y = f2bf(acc[m][n][1]);
          pk.z = f2bf(acc[m][n][2]);
          pk.w = f2bf(acc[m][n][3]);
          *(ushort4*)(vb + (bhi * 64 + d) * 2048 + pos) = pk;  // V^T [BH][64][Tperm]
        }
      }
    }
  }
}

// ------------------------------------------------------------- attention
// Q: [BH][2048][64] bf16 pre-scaled by 0.125*log2e.  K: [BH][2048][64] bf16.
// Vt: [BH][64][2048] bf16 (key-permuted).  Ab out: [B][T][H*64] bf16.
// Block bid: qt = 31 - bid/64 (longest-first), bh = bid & 63.
// 4 waves; wave w owns q rows [qt*64 + w*16, +16). K/V tiles staged in LDS
// (double-buffered, XOR-swizzled). Swapped QK^T -> in-register softmax ->
// P-frag bit-cast straight from cvt_pk words. exp2 domain, diagonal-only
// mask, defer-max THR=8. amdgpu_waves_per_eu(4,4): pin occupancy target so
// the allocator spends its 128-VGPR budget instead of spilling toward 8 waves.
// All hot-loop state in named values (no arrays) so SROA keeps it in SSA.
#define QK_TILE(SV, KT)                                                      \
  {                                                                          \
    const int krow = (KT) * 16 + l15;                                        \
    const int sw = krow & 7;                                                 \
    bf16x8 kf0 = *(const bf16x8*)&Ks[cur][krow * 64 + ((lhi ^ sw) * 8)];     \
    bf16x8 kf1 = *(const bf16x8*)&Ks[cur][krow * 64 + (((4 + lhi) ^ sw) * 8)];\
    f32x4 acc_ = {};                                                         \
    acc_ = MFMA_BF16(kf0, qf0, acc_);                                        \
    acc_ = MFMA_BF16(kf1, qf1, acc_);                                        \
    SV = acc_;                                                               \
  }

#define MASK_TILE(SV, KT)                                                    \
  {                                                                          \
    if (key0 + (KT) * 16 + lhi * 4 + 0 > qrow) SV[0] = -INFINITY;            \
    if (key0 + (KT) * 16 + lhi * 4 + 1 > qrow) SV[1] = -INFINITY;            \
    if (key0 + (KT) * 16 + lhi * 4 + 2 > qrow) SV[2] = -INFINITY;            \
    if (key0 + (KT) * 16 + lhi * 4 + 3 > qrow) SV[3] = -INFINITY;            \
  }

#define SM_TILE(SV, W0, W1)                                                  \
  {                                                                          \
    float p0 = exp2f(SV[0] - m_state);                                       \
    float p1 = exp2f(SV[1] - m_state);                                       \
    float p2 = exp2f(SV[2] - m_state);                                       \
    float p3 = exp2f(SV[3] - m_state);                                       \
    lloc += (p0 + p1) + (p2 + p3);                                           \
    W0 = cvt_pk_bf16(p0, p1);                                                \
    W1 = cvt_pk_bf16(p2, p3);                                                \
  }

#define PV_TILE(ON, N)                                                       \
  {                                                                          \
    const int vrow = (N) * 16 + l15;                                         \
    const int sw = vrow & 7;                                                 \
    bf16x8 vf0 = *(const bf16x8*)&Vs[cur][vrow * 64 + ((lhi ^ sw) * 8)];     \
    bf16x8 vf1 = *(const bf16x8*)&Vs[cur][vrow * 64 + (((4 + lhi) ^ sw) * 8)];\
    ON = MFMA_BF16(pf0, vf0, ON);                                            \
    ON = MFMA_BF16(pf1, vf1, ON);                                            \
  }

__global__ __launch_bounds__(256)
__attribute__((amdgpu_waves_per_eu(4, 4)))
void attn_kernel(
    const ushort* __restrict__ Qb, const ushort* __restrict__ Kb,
    const ushort* __restrict__ Vt, ushort* __restrict__ Ab) {
  const int bid = blockIdx.x;
  const int qt = 31 - (bid >> 6);
  const int bh = bid & 63;
  const int tid = threadIdx.x;
  const int lane = tid & 63;
  const int w = tid >> 6;
  const int l15 = lane & 15, lhi = lane >> 4;
  const int qloc = qt * 64 + w * 16;

  __shared__ ushort Ks[2][64 * 64];  // swizzled: elem = key*64 + ((d/8)^(key&7))*8 + d%8
  __shared__ ushort Vs[2][64 * 64];  // swizzled: elem = d*64 + ((p/8)^(d&7))*8 + p%8

  const size_t qkbase = (size_t)bh * (2048 * 64);
  const size_t vtb = (size_t)bh * (64 * 2048);

  // staging geometry: wave w covers tile rows [w*16, w*16+16), rows srow, srow+8
  const int srow = w * 16 + (lane >> 3);
  const int sd0 = lane & 7;                    // 16B slot within 128B row
  const int slot = (sd0 ^ (srow & 7)) * 8;     // same for srow and srow+8

  const ushort* kp0 = Kb + qkbase + (size_t)srow * 64 + sd0 * 8;
  const ushort* kp1 = kp0 + 8 * 64;
  const ushort* vp0 = Vt + vtb + (size_t)srow * 2048 + sd0 * 8;
  const ushort* vp1 = vp0 + 8 * 2048;

  bf16x8 qf0 = *(const bf16x8*)(Qb + qkbase + (size_t)(qloc + l15) * 64 + lhi * 8);
  bf16x8 qf1 = *(const bf16x8*)(Qb + qkbase + (size_t)(qloc + l15) * 64 + 32 + lhi * 8);

  // ---- prologue: stage tile 0
  uint4 kr0 = *(const uint4*)kp0;
  uint4 kr1 = *(const uint4*)kp1;
  uint4 vr0 = *(const uint4*)vp0;
  uint4 vr1 = *(const uint4*)vp1;
  *(uint4*)&Ks[0][srow * 64 + slot] = kr0;
  *(uint4*)&Ks[0][(srow + 8) * 64 + slot] = kr1;
  *(uint4*)&Vs[0][srow * 64 + slot] = vr0;
  *(uint4*)&Vs[0][(srow + 8) * 64 + slot] = vr1;
  __syncthreads();

  float m_state = -INFINITY, l_state = 0.f;
  f32x4 o0 = {}, o1 = {}, o2 = {}, o3 = {};
  const int qrow = qloc + l15;
  int cur = 0;

  for (int kbt = 0; kbt <= qt; ++kbt) {
    const int key0 = kbt * 64;
    const bool last = (kbt == qt);  // block-uniform

    // ---- issue prefetch loads for tile kbt+1 (latency hides under compute)
    if (!last) {
      const size_t koff = (size_t)(kbt + 1) * 64 * 64;  // 64 rows x 64 d
      kr0 = *(const uint4*)(kp0 + koff);
      kr1 = *(const uint4*)(kp1 + koff);
      vr0 = *(const uint4*)(vp0 + (kbt + 1) * 64);
      vr1 = *(const uint4*)(vp1 + (kbt + 1) * 64);
    }

    // ---- S^T = K Q^T from LDS (lane: q-col l15, key rows kt*16+lhi*4+j)
    f32x4 s0, s1, s2, s3;
    __builtin_amdgcn_s_setprio(1);
    QK_TILE(s0, 0)
    QK_TILE(s1, 1)
    QK_TILE(s2, 2)
    QK_TILE(s3, 3)
    __builtin_amdgcn_s_setprio(0);

    // ---- causal mask: only the diagonal tile needs it (wave-uniform branch)
    if (last) {
      MASK_TILE(s0, 0)
      MASK_TILE(s1, 1)
      MASK_TILE(s2, 2)
      MASK_TILE(s3, 3)
    }

    // ---- tile max (exp2 domain; no scale mul)
    float t0 = fmaxf(fmaxf(s0[0], s0[1]), fmaxf(s0[2], s0[3]));
    float t1 = fmaxf(fmaxf(s1[0], s1[1]), fmaxf(s1[2], s1[3]));
    float t2 = fmaxf(fmaxf(s2[0], s2[1]), fmaxf(s2[2], s2[3]));
    float t3 = fmaxf(fmaxf(s3[0], s3[1]), fmaxf(s3[2], s3[3]));
    float tmax = fmaxf(fmaxf(t0, t1), fmaxf(t2, t3));
    tmax = fmaxf(tmax, __shfl_xor(tmax, 16));
    tmax = fmaxf(tmax, __shfl_xor(tmax, 32));

    // ---- defer-max: rescale only when the running max grows by > 8
    if (!__all(tmax <= m_state + 8.0f)) {
      const float mnew = fmaxf(m_state, tmax);
      const float alpha = exp2f(m_state - mnew);  // first tile: exp2(-inf)=0
      const float a0 = __shfl(alpha, lhi * 4 + 0);
      const float a1 = __shfl(alpha, lhi * 4 + 1);
      const float a2 = __shfl(alpha, lhi * 4 + 2);
      const float a3 = __shfl(alpha, lhi * 4 + 3);
      o0[0] *= a0; o0[1] *= a1; o0[2] *= a2; o0[3] *= a3;
      o1[0] *= a0; o1[1] *= a1; o1[2] *= a2; o1[3] *= a3;
      o2[0] *= a0; o2[1] *= a1; o2[2] *= a2; o2[3] *= a3;
      o3[0] *= a0; o3[1] *= a1; o3[2] *= a2; o3[3] *= a3;
      l_state *= alpha;
      m_state = mnew;
    }

    // ---- exp2 + row-sum + pack P into registers (A-frag via V permutation)
    float lloc = 0.f;
    uint32_t w0, w1, w2, w3, w4, w5, w6, w7;
    SM_TILE(s0, w0, w1)
    SM_TILE(s1, w2, w3)
    SM_TILE(s2, w4, w5)
    SM_TILE(s3, w6, w7)
    lloc += __shfl_xor(lloc, 16);
    lloc += __shfl_xor(lloc, 32);
    l_state += lloc;

    u32x4 pw0 = {w0, w1, w2, w3};
    u32x4 pw1 = {w4, w5, w6, w7};
    bf16x8 pf0 = __builtin_bit_cast(bf16x8, pw0);  // keys(perm-pos) 0..31
    bf16x8 pf1 = __builtin_bit_cast(bf16x8, pw1);  // keys(perm-pos) 32..63

    // ---- O += P V from LDS (register P-frags; V key-permuted to match)
    __builtin_amdgcn_s_setprio(1);
    PV_TILE(o0, 0)
    PV_TILE(o1, 1)
    PV_TILE(o2, 2)
    PV_TILE(o3, 3)
    __builtin_amdgcn_s_setprio(0);

    // ---- commit prefetched tile to the other buffer; one barrier per iter
    if (!last) {
      const int nxt = cur ^ 1;
      *(uint4*)&Ks[nxt][srow * 64 + slot] = kr0;
      *(uint4*)&Ks[nxt][(srow + 8) * 64 + slot] = kr1;
      *(uint4*)&Vs[nxt][srow * 64 + slot] = vr0;
      *(uint4*)&Vs[nxt][(srow + 8) * 64 + slot] = vr1;
      cur = nxt;
      __syncthreads();
    }
  }

  // ---- epilogue: normalize by l (state lives at lane=row), store bf16
  const int b_ = bh >> 4, h_ = bh & 15;
#pragma unroll
  for (int j = 0; j < 4; ++j) {
    const float linv = 1.0f / __shfl(l_state, lhi * 4 + j);
    const int t = qloc + lhi * 4 + j;
    const size_t ro = ((size_t)b_ * 2048 + t) * 1024 + h_ * 64;
    Ab[ro + 0 * 16 + l15] = f2bf(o0[j] * linv);
    Ab[ro + 1 * 16 + l15] = f2bf(o1[j] * linv);
    Ab[ro + 2 * 16 + l15] = f2bf(o2[j] * linv);
    Ab[ro + 3 * 16 + l15] = f2bf(o3[j] * linv);
  }
}

// ---------------------------------------------------------------- launch
extern "C" void kernel_launch(void* const* d_in, const int* in_sizes, int n_in,
                              void* d_out, int out_size, void* d_ws, size_t ws_size,
                              hipStream_t stream) {
  const float* x = (const float*)d_in[0];
  const float* Wqkv = (const float*)d_in[1];
  const float* Wout = (const float*)d_in[2];
  float* out = (float*)d_out;

  // workspace layout (bf16 elements), total ~88 MB
  ushort* xb    = (ushort*)d_ws;                     // [8192][1024]
  ushort* wqkvT = xb + (size_t)8192 * 1024;          // [3072][1024]
  ushort* woutT = wqkvT + (size_t)3072 * 1024;       // [1024][1024]
  ushort* qb    = woutT + (size_t)1024 * 1024;       // [64][2048][64]
  ushort* kbuf  = qb + (size_t)64 * 2048 * 64;       // [64][2048][64]
  ushort* vbuf  = kbuf + (size_t)64 * 2048 * 64;     // [64][64][2048] (V^T, key-permuted)
  ushort* ab    = vbuf + (size_t)64 * 2048 * 64;     // [8192][1024]

  convert_f32_bf16<<<8192, 256, 0, stream>>>(x, xb, 8192 * 1024 / 4);
  transpose_w<<<dim3(96, 32), 256, 0, stream>>>(Wqkv, wqkvT, 1024, 3072);
  transpose_w<<<dim3(32, 32), 256, 0, stream>>>(Wout, woutT, 1024, 1024);
  gemm_bf16_kernel<0><<<dim3(64, 24), 256, 0, stream>>>(
      xb, wqkvT, nullptr, qb, kbuf, vbuf, 8192, 3072, 1024);
  attn_kernel<<<2048, 256, 0, stream>>>(qb, kbuf, vbuf, ab);
  gemm_bf16_kernel<1><<<dim3(64, 8), 256, 0, stream>>>(
      ab, woutT, out, nullptr, nullptr, nullptr, 8192, 1024, 1024);
}

// Round 9
// 173.790 us; speedup vs baseline: 1.3929x; 1.1231x over previous
//
#include <hip/hip_runtime.h>
#include <hip/hip_bf16.h>
#include <cstdint>

// Causal self-attention: x[4,2048,1024] @ Wqkv[1024,3072] -> QKV -> 16-head
// causal attention (HD=64) -> @ Wout[1024,1024] -> out fp32.
// R9: GEMM rebuilt: BK=64, double-buffered LDS (64KB, 2 blocks/CU), all 8
// global_load_lds for tile t+1 issued BEFORE computing tile t (one barrier
// per iter, drain hidden under compute), and XOR-swizzled LDS via
// pre-swizzled global source (linear DMA dest) + swizzled ds_read -> minimum
// bank aliasing. waves_per_eu(2,2) pins the 256-VGPR budget (no spill).
// Attention unchanged from R8 (spill fixed, ~50us).

typedef __attribute__((ext_vector_type(8))) short bf16x8;
typedef __attribute__((ext_vector_type(4))) float f32x4;
typedef __attribute__((ext_vector_type(4))) uint32_t u32x4;

#define MFMA_BF16(a, b, c) __builtin_amdgcn_mfma_f32_16x16x32_bf16((a), (b), (c), 0, 0, 0)

__device__ __forceinline__ ushort f2bf(float f) {
  union { float f; uint32_t u; } x;
  x.f = f;
  uint32_t u = x.u;
  return (ushort)((u + 0x7FFFu + ((u >> 16) & 1u)) >> 16);
}

__device__ __forceinline__ uint32_t cvt_pk_bf16(float lo, float hi) {
  uint32_t r;
  asm("v_cvt_pk_bf16_f32 %0, %1, %2" : "=v"(r) : "v"(lo), "v"(hi));
  return r;
}

__device__ __forceinline__ void gload16(const ushort* g, ushort* l) {
  __builtin_amdgcn_global_load_lds(
      (const __attribute__((address_space(1))) void*)g,
      (__attribute__((address_space(3))) void*)l, 16, 0, 0);
}

// ---------------------------------------------------------------- convert x
__global__ __launch_bounds__(256) void convert_f32_bf16(
    const float* __restrict__ in, ushort* __restrict__ out, int n4) {
  int i = blockIdx.x * 256 + threadIdx.x;
  if (i < n4) {
    float4 v = ((const float4*)in)[i];
    ushort4 o;
    o.x = f2bf(v.x); o.y = f2bf(v.y); o.z = f2bf(v.z); o.w = f2bf(v.w);
    ((ushort4*)out)[i] = o;
  }
}

// ------------------------------------------------- W [K][N] f32 -> Wt [N][K] bf16
__global__ __launch_bounds__(256) void transpose_w(
    const float* __restrict__ W, ushort* __restrict__ Wt, int K, int N) {
  __shared__ float tile[32][33];
  const int n0 = blockIdx.x * 32, k0 = blockIdx.y * 32;
  const int tx = threadIdx.x & 31, ty = threadIdx.x >> 5;  // ty 0..7
#pragma unroll
  for (int i = 0; i < 4; ++i)
    tile[ty + i * 8][tx] = W[(size_t)(k0 + ty + i * 8) * N + n0 + tx];
  __syncthreads();
#pragma unroll
  for (int i = 0; i < 4; ++i)
    Wt[(size_t)(n0 + ty + i * 8) * K + k0 + tx] = f2bf(tile[tx][ty + i * 8]);
}

// ---------------------------------------------------------------- GEMM bf16
// A [M][K] bf16 row-major, Bt [N][K] bf16 row-major (B transposed).
// 128x128 tile, BK=64, double-buffered LDS [2][128][64] (ushort, linear for
// global_load_lds DMA). Swizzle: LDS[row][ (s ^ (row&7))*8 .. ] holds global
// granule s of that row, achieved by pre-swizzling the per-lane global source
// (g = sl ^ cr) and XOR-ing the ds_read slot. Tile t+1's 8 gload_lds issued
// before tile t's MFMAs; single barrier per iteration drains them under
// compute. waves_per_eu(2,2): 2 blocks/CU (64KB LDS), 256-VGPR budget.
// MODE 0: epilogue splits QKV -> q (pre-scaled 0.125*log2e), k [BH][T][64],
//         v transposed [BH][64][T] with keys permuted within 32-chunks.
// MODE 1: epilogue stores fp32 C [M][N].
template <int MODE>
__global__ __launch_bounds__(256)
__attribute__((amdgpu_waves_per_eu(2, 2)))
void gemm_bf16_kernel(
    const ushort* __restrict__ A, const ushort* __restrict__ Bt,
    float* __restrict__ C,
    ushort* __restrict__ qb, ushort* __restrict__ kb, ushort* __restrict__ vb,
    int M, int N, int K) {
  __shared__ ushort As[2][128 * 64];
  __shared__ ushort Bs[2][128 * 64];
  const int tid = threadIdx.x;
  const int lane = tid & 63;
  const int w = tid >> 6;
  const int wr = w >> 1, wc = w & 1;
  const int l15 = lane & 15, lhi = lane >> 4;
  const int row0 = blockIdx.x * 128, col0 = blockIdx.y * 128;

  // staging: per K-tile, A = 128x64 ushort = 16 chunks of 1KB; wave w stages
  // chunks [w*4, w*4+4) of A and of B. Lane L -> row cr=L>>3 in chunk, slot
  // sl=L&7 (linear LDS). Global granule = sl ^ cr (row&7 == cr for all chunks).
  const int cr = lane >> 3;
  const int sl = lane & 7;
  const int gofs = (sl ^ cr) << 3;  // ushort offset within the 64-col row
  const ushort* gA = A  + (size_t)(row0 + w * 32 + cr) * K + gofs;
  const ushort* gB = Bt + (size_t)(col0 + w * 32 + cr) * K + gofs;
  const int lbase = (w * 32) * 64;  // ushort index of this wave's chunk 0

  f32x4 acc[4][4] = {};

#define G_STAGE(BUF, K0)                                                     \
  {                                                                          \
    _Pragma("unroll")                                                        \
    for (int i = 0; i < 4; ++i) {                                            \
      gload16(gA + (size_t)(i * 8) * K + (K0), &As[BUF][lbase + i * 512]);   \
      gload16(gB + (size_t)(i * 8) * K + (K0), &Bs[BUF][lbase + i * 512]);   \
    }                                                                        \
  }

  const int nk = K >> 6;
  G_STAGE(0, 0)
  __syncthreads();

  for (int t = 0; t < nk; ++t) {
    const int cur = t & 1;
    if (t + 1 < nk) G_STAGE(cur ^ 1, (t + 1) << 6)

#pragma unroll
    for (int kh = 0; kh < 2; ++kh) {
      bf16x8 af[4], bfr[4];
#pragma unroll
      for (int m = 0; m < 4; ++m) {
        const int row = wr * 64 + m * 16 + l15;
        const int s = kh * 4 + lhi;
        af[m] = *(const bf16x8*)&As[cur][row * 64 + ((s ^ (row & 7)) << 3)];
      }
#pragma unroll
      for (int n = 0; n < 4; ++n) {
        const int row = wc * 64 + n * 16 + l15;
        const int s = kh * 4 + lhi;
        bfr[n] = *(const bf16x8*)&Bs[cur][row * 64 + ((s ^ (row & 7)) << 3)];
      }
      __builtin_amdgcn_s_setprio(1);
#pragma unroll
      for (int m = 0; m < 4; ++m)
#pragma unroll
        for (int n = 0; n < 4; ++n)
          acc[m][n] = MFMA_BF16(af[m], bfr[n], acc[m][n]);
      __builtin_amdgcn_s_setprio(0);
    }
    __syncthreads();  // drains t+1's gload_lds (hidden under this tile's MFMAs)
  }
#undef G_STAGE

  if (MODE == 1) {
#pragma unroll
    for (int m = 0; m < 4; ++m) {
      const int r0 = row0 + wr * 64 + m * 16 + lhi * 4;
#pragma unroll
      for (int n = 0; n < 4; ++n) {
        const int c = col0 + wc * 64 + n * 16 + l15;
#pragma unroll
        for (int j = 0; j < 4; ++j)
          C[(size_t)(r0 + j) * N + c] = acc[m][n][j];
      }
    }
  } else {
    // QKV split epilogue. c in [0,3072): seg = c/1024 (q/k/v), h = (c%1024)/64, d = c%64
    const float QSCALE = 0.18033688011112042f;  // (1/sqrt(64)) * log2(e)
#pragma unroll
    for (int m = 0; m < 4; ++m) {
      const int r0 = row0 + wr * 64 + m * 16 + lhi * 4;  // global token row (4 consecutive)
      const int b_ = r0 >> 11;
      const int t0 = r0 & 2047;
#pragma unroll
      for (int n = 0; n < 4; ++n) {
        const int c = col0 + wc * 64 + n * 16 + l15;
        const int seg = c >> 10;
        const int cc = c & 1023;
        const int h = cc >> 6, d = cc & 63;
        const size_t bhi = (size_t)(b_ * 16 + h);
        if (seg == 0) {
#pragma unroll
          for (int j = 0; j < 4; ++j)
            qb[(bhi * 2048 + t0 + j) * 64 + d] = f2bf(acc[m][n][j] * QSCALE);
        } else if (seg == 1) {
#pragma unroll
          for (int j = 0; j < 4; ++j)
            kb[(bhi * 2048 + t0 + j) * 64 + d] = f2bf(acc[m][n][j]);
        } else {
          // permuted key position within the 32-token chunk (t0 % 4 == 0)
          const int pos = (t0 & ~31) + ((t0 & 12) << 1) + ((t0 >> 4) & 1) * 4;
          ushort4 pk;
          pk.x = f2bf(acc[m][n][0]);
          pk.y = f2bf(acc[m][n][1]);
          pk.z = f2bf(acc[m][n][2]);
          pk.w = f2bf(acc[m][n][3]);
          *(ushort4*)(vb + (bhi * 64 + d) * 2048 + pos) = pk;  // V^T [BH][64][Tperm]
        }
      }
    }
  }
}

// ------------------------------------------------------------- attention
// (unchanged from R8 — spill fixed via waves_per_eu(4,4) + de-arrayed state)
#define QK_TILE(SV, KT)                                                      \
  {                                                                          \
    const int krow = (KT) * 16 + l15;                                        \
    const int sw = krow & 7;                                                 \
    bf16x8 kf0 = *(const bf16x8*)&Ks[cur][krow * 64 + ((lhi ^ sw) * 8)];     \
    bf16x8 kf1 = *(const bf16x8*)&Ks[cur][krow * 64 + (((4 + lhi) ^ sw) * 8)];\
    f32x4 acc_ = {};                                                         \
    acc_ = MFMA_BF16(kf0, qf0, acc_);                                        \
    acc_ = MFMA_BF16(kf1, qf1, acc_);                                        \
    SV = acc_;                                                               \
  }

#define MASK_TILE(SV, KT)                                                    \
  {                                                                          \
    if (key0 + (KT) * 16 + lhi * 4 + 0 > qrow) SV[0] = -INFINITY;            \
    if (key0 + (KT) * 16 + lhi * 4 + 1 > qrow) SV[1] = -INFINITY;            \
    if (key0 + (KT) * 16 + lhi * 4 + 2 > qrow) SV[2] = -INFINITY;            \
    if (key0 + (KT) * 16 + lhi * 4 + 3 > qrow) SV[3] = -INFINITY;            \
  }

#define SM_TILE(SV, W0, W1)                                                  \
  {                                                                          \
    float p0 = exp2f(SV[0] - m_state);                                       \
    float p1 = exp2f(SV[1] - m_state);                                       \
    float p2 = exp2f(SV[2] - m_state);                                       \
    float p3 = exp2f(SV[3] - m_state);                                       \
    lloc += (p0 + p1) + (p2 + p3);                                           \
    W0 = cvt_pk_bf16(p0, p1);                                                \
    W1 = cvt_pk_bf16(p2, p3);                                                \
  }

#define PV_TILE(ON, N)                                                       \
  {                                                                          \
    const int vrow = (N) * 16 + l15;                                         \
    const int sw = vrow & 7;                                                 \
    bf16x8 vf0 = *(const bf16x8*)&Vs[cur][vrow * 64 + ((lhi ^ sw) * 8)];     \
    bf16x8 vf1 = *(const bf16x8*)&Vs[cur][vrow * 64 + (((4 + lhi) ^ sw) * 8)];\
    ON = MFMA_BF16(pf0, vf0, ON);                                            \
    ON = MFMA_BF16(pf1, vf1, ON);                                            \
  }

__global__ __launch_bounds__(256)
__attribute__((amdgpu_waves_per_eu(4, 4)))
void attn_kernel(
    const ushort* __restrict__ Qb, const ushort* __restrict__ Kb,
    const ushort* __restrict__ Vt, ushort* __restrict__ Ab) {
  const int bid = blockIdx.x;
  const int qt = 31 - (bid >> 6);
  const int bh = bid & 63;
  const int tid = threadIdx.x;
  const int lane = tid & 63;
  const int w = tid >> 6;
  const int l15 = lane & 15, lhi = lane >> 4;
  const int qloc = qt * 64 + w * 16;

  __shared__ ushort Ks[2][64 * 64];  // swizzled: elem = key*64 + ((d/8)^(key&7))*8 + d%8
  __shared__ ushort Vs[2][64 * 64];  // swizzled: elem = d*64 + ((p/8)^(d&7))*8 + p%8

  const size_t qkbase = (size_t)bh * (2048 * 64);
  const size_t vtb = (size_t)bh * (64 * 2048);

  const int srow = w * 16 + (lane >> 3);
  const int sd0 = lane & 7;                    // 16B slot within 128B row
  const int slot = (sd0 ^ (srow & 7)) * 8;     // same for srow and srow+8

  const ushort* kp0 = Kb + qkbase + (size_t)srow * 64 + sd0 * 8;
  const ushort* kp1 = kp0 + 8 * 64;
  const ushort* vp0 = Vt + vtb + (size_t)srow * 2048 + sd0 * 8;
  const ushort* vp1 = vp0 + 8 * 2048;

  bf16x8 qf0 = *(const bf16x8*)(Qb + qkbase + (size_t)(qloc + l15) * 64 + lhi * 8);
  bf16x8 qf1 = *(const bf16x8*)(Qb + qkbase + (size_t)(qloc + l15) * 64 + 32 + lhi * 8);

  // ---- prologue: stage tile 0
  uint4 kr0 = *(const uint4*)kp0;
  uint4 kr1 = *(const uint4*)kp1;
  uint4 vr0 = *(const uint4*)vp0;
  uint4 vr1 = *(const uint4*)vp1;
  *(uint4*)&Ks[0][srow * 64 + slot] = kr0;
  *(uint4*)&Ks[0][(srow + 8) * 64 + slot] = kr1;
  *(uint4*)&Vs[0][srow * 64 + slot] = vr0;
  *(uint4*)&Vs[0][(srow + 8) * 64 + slot] = vr1;
  __syncthreads();

  float m_state = -INFINITY, l_state = 0.f;
  f32x4 o0 = {}, o1 = {}, o2 = {}, o3 = {};
  const int qrow = qloc + l15;
  int cur = 0;

  for (int kbt = 0; kbt <= qt; ++kbt) {
    const int key0 = kbt * 64;
    const bool last = (kbt == qt);  // block-uniform

    if (!last) {
      const size_t koff = (size_t)(kbt + 1) * 64 * 64;
      kr0 = *(const uint4*)(kp0 + koff);
      kr1 = *(const uint4*)(kp1 + koff);
      vr0 = *(const uint4*)(vp0 + (kbt + 1) * 64);
      vr1 = *(const uint4*)(vp1 + (kbt + 1) * 64);
    }

    f32x4 s0, s1, s2, s3;
    __builtin_amdgcn_s_setprio(1);
    QK_TILE(s0, 0)
    QK_TILE(s1, 1)
    QK_TILE(s2, 2)
    QK_TILE(s3, 3)
    __builtin_amdgcn_s_setprio(0);

    if (last) {
      MASK_TILE(s0, 0)
      MASK_TILE(s1, 1)
      MASK_TILE(s2, 2)
      MASK_TILE(s3, 3)
    }

    float t0 = fmaxf(fmaxf(s0[0], s0[1]), fmaxf(s0[2], s0[3]));
    float t1 = fmaxf(fmaxf(s1[0], s1[1]), fmaxf(s1[2], s1[3]));
    float t2 = fmaxf(fmaxf(s2[0], s2[1]), fmaxf(s2[2], s2[3]));
    float t3 = fmaxf(fmaxf(s3[0], s3[1]), fmaxf(s3[2], s3[3]));
    float tmax = fmaxf(fmaxf(t0, t1), fmaxf(t2, t3));
    tmax = fmaxf(tmax, __shfl_xor(tmax, 16));
    tmax = fmaxf(tmax, __shfl_xor(tmax, 32));

    if (!__all(tmax <= m_state + 8.0f)) {
      const float mnew = fmaxf(m_state, tmax);
      const float alpha = exp2f(m_state - mnew);
      const float a0 = __shfl(alpha, lhi * 4 + 0);
      const float a1 = __shfl(alpha, lhi * 4 + 1);
      const float a2 = __shfl(alpha, lhi * 4 + 2);
      const float a3 = __shfl(alpha, lhi * 4 + 3);
      o0[0] *= a0; o0[1] *= a1; o0[2] *= a2; o0[3] *= a3;
      o1[0] *= a0; o1[1] *= a1; o1[2] *= a2; o1[3] *= a3;
      o2[0] *= a0; o2[1] *= a1; o2[2] *= a2; o2[3] *= a3;
      o3[0] *= a0; o3[1] *= a1; o3[2] *= a2; o3[3] *= a3;
      l_state *= alpha;
      m_state = mnew;
    }

    float lloc = 0.f;
    uint32_t w0, w1, w2, w3, w4, w5, w6, w7;
    SM_TILE(s0, w0, w1)
    SM_TILE(s1, w2, w3)
    SM_TILE(s2, w4, w5)
    SM_TILE(s3, w6, w7)
    lloc += __shfl_xor(lloc, 16);
    lloc += __shfl_xor(lloc, 32);
    l_state += lloc;

    u32x4 pw0 = {w0, w1, w2, w3};
    u32x4 pw1 = {w4, w5, w6, w7};
    bf16x8 pf0 = __builtin_bit_cast(bf16x8, pw0);
    bf16x8 pf1 = __builtin_bit_cast(bf16x8, pw1);

    __builtin_amdgcn_s_setprio(1);
    PV_TILE(o0, 0)
    PV_TILE(o1, 1)
    PV_TILE(o2, 2)
    PV_TILE(o3, 3)
    __builtin_amdgcn_s_setprio(0);

    if (!last) {
      const int nxt = cur ^ 1;
      *(uint4*)&Ks[nxt][srow * 64 + slot] = kr0;
      *(uint4*)&Ks[nxt][(srow + 8) * 64 + slot] = kr1;
      *(uint4*)&Vs[nxt][srow * 64 + slot] = vr0;
      *(uint4*)&Vs[nxt][(srow + 8) * 64 + slot] = vr1;
      cur = nxt;
      __syncthreads();
    }
  }

  const int b_ = bh >> 4, h_ = bh & 15;
#pragma unroll
  for (int j = 0; j < 4; ++j) {
    const float linv = 1.0f / __shfl(l_state, lhi * 4 + j);
    const int t = qloc + lhi * 4 + j;
    const size_t ro = ((size_t)b_ * 2048 + t) * 1024 + h_ * 64;
    Ab[ro + 0 * 16 + l15] = f2bf(o0[j] * linv);
    Ab[ro + 1 * 16 + l15] = f2bf(o1[j] * linv);
    Ab[ro + 2 * 16 + l15] = f2bf(o2[j] * linv);
    Ab[ro + 3 * 16 + l15] = f2bf(o3[j] * linv);
  }
}

// ---------------------------------------------------------------- launch
extern "C" void kernel_launch(void* const* d_in, const int* in_sizes, int n_in,
                              void* d_out, int out_size, void* d_ws, size_t ws_size,
                              hipStream_t stream) {
  const float* x = (const float*)d_in[0];
  const float* Wqkv = (const float*)d_in[1];
  const float* Wout = (const float*)d_in[2];
  float* out = (float*)d_out;

  // workspace layout (bf16 elements), total ~88 MB
  ushort* xb    = (ushort*)d_ws;                     // [8192][1024]
  ushort* wqkvT = xb + (size_t)8192 * 1024;          // [3072][1024]
  ushort* woutT = wqkvT + (size_t)3072 * 1024;       // [1024][1024]
  ushort* qb    = woutT + (size_t)1024 * 1024;       // [64][2048][64]
  ushort* kbuf  = qb + (size_t)64 * 2048 * 64;       // [64][2048][64]
  ushort* vbuf  = kbuf + (size_t)64 * 2048 * 64;     // [64][64][2048] (V^T, key-permuted)
  ushort* ab    = vbuf + (size_t)64 * 2048 * 64;     // [8192][1024]

  convert_f32_bf16<<<8192, 256, 0, stream>>>(x, xb, 8192 * 1024 / 4);
  transpose_w<<<dim3(96, 32), 256, 0, stream>>>(Wqkv, wqkvT, 1024, 3072);
  transpose_w<<<dim3(32, 32), 256, 0, stream>>>(Wout, woutT, 1024, 1024);
  gemm_bf16_kernel<0><<<dim3(64, 24), 256, 0, stream>>>(
      xb, wqkvT, nullptr, qb, kbuf, vbuf, 8192, 3072, 1024);
  attn_kernel<<<2048, 256, 0, stream>>>(qb, kbuf, vbuf, ab);
  gemm_bf16_kernel<1><<<dim3(64, 8), 256, 0, stream>>>(
      ab, woutT, out, nullptr, nullptr, nullptr, 8192, 1024, 1024);
}